// Round 5
// baseline (333.707 us; speedup 1.0000x reference)
//
#include <hip/hip_runtime.h>

#define HW_   (512 * 512)   // pixels per image
#define NIMG  8
#define NC    19            // classes
#define NSP   2048          // superpixels per image
#define TC    20            // target row stride (C+1, last col sliced off)
#define NROWS (NIMG * NSP)  // 16384 target rows
#define TILE  1024          // pixels per tile (4 per thread)
#define NBLK  (NIMG * HW_ / TILE)   // 2048 single-tile blocks
#define NGRP  16            // completion-ticket groups (128 blocks each)
#define GSIZE (NBLK / NGRP)

typedef float vf4 __attribute__((ext_vector_type(4)));
typedef int   vi4 __attribute__((ext_vector_type(4)));

// d_ws layout:
//   [0]     flag (uint)       spmask width: 1 -> 4-byte, 0 -> 1-byte
//   [4]     st   (uint)       super ticket
//   [64]    gt[NGRP] uints, stride 16 (64 B apart -> no same-line RMWs)
//   [1088]  pl[NBLK] float    per-block loss partials (contention-free)
//   [9280]  pc[NBLK] uint     per-block count partials
//   [17472] bmt[NROWS] uint   per-(image,superpixel) multi-hot bitmask

// ---------------------------------------------------------------------------
// Kernel 1 (separate small dispatch, ~few us): zero tickets, detect spmask
// width, build target bitmasks. Bit c set iff targets[n,s,c] != 0.
// ---------------------------------------------------------------------------
__global__ __launch_bounds__(256) void prep(
    const float* __restrict__ tgt,
    const unsigned int* __restrict__ spm,
    unsigned int* __restrict__ flag, unsigned int* __restrict__ st,
    unsigned int* __restrict__ gt, unsigned int* __restrict__ bm) {

    int gid = blockIdx.x * 256 + threadIdx.x;   // 64 blocks -> 16384 threads
    if (gid == 0) *st = 0u;
    if (gid < NGRP) gt[gid * 16] = 0u;

    if (blockIdx.x == 1 && threadIdx.x < 64) {  // one wave: width detection
        unsigned int nonlow = 0, upper = 0;
        for (int i = threadIdx.x; i < 1024; i += 64) {
            unsigned int v = spm[i];
            nonlow |= (v & 0xFEFEFEFEu);
            upper  |= (v & 0xFFFFFF00u);
        }
        unsigned long long b1 = __ballot(nonlow != 0);
        unsigned long long b2 = __ballot(upper != 0);
        if (threadIdx.x == 0)
            *flag = ((b1 == 0ull) && (b2 != 0ull)) ? 0u : 1u;
    }

    const float* row = tgt + (size_t)gid * TC;  // one thread per target row
    unsigned int m = 0;
#pragma unroll
    for (int c = 0; c < NC; ++c)
        m |= (row[c] != 0.0f ? 1u : 0u) << c;
    bm[gid] = m;
}

// ---------------------------------------------------------------------------
// Kernel 2: single-tile blocks, R1's image-serial 20-load burst, R3's
// no-spill counted-vmcnt chunk consumption.
//   - 2048 blocks x 256 threads, block b owns tile b (n = b>>8). Dispatch
//     proceeds in roughly ascending b -> live tiles span ~2-4 images, and
//     the dispatcher rotates FRESH blocks (fresh bursts) onto CUs as others
//     finish: continuous burst/VALU overlap instead of R1's four chip-
//     synchronized stall phases.
//   - The 20 dwordx4 burst is one asm block (indivisible, outputs live, no
//     compiler waits inside). vmcnt(19) frees s4 so the 4 bitmask gathers
//     and the spmask load issue UNDER the stream; exp+denominator chunks
//     retire at vmcnt(15/11/7/3/0) (register-tied, in-place exp -> no dv
//     copy, no spill: WRITE_SIZE must stay ~0; R1's 96 MB came from the
//     dv[NC] init doubling live regs).
//   - ts (numerator) pass runs after the chunks from the d-reg aliases,
//     ascending class order -> per-pixel FP order identical to R1/R3.
// ---------------------------------------------------------------------------
__global__ __launch_bounds__(256, 4) void mcce_main(
    const float* __restrict__ x,      // (N, C, H*W)
    const int*   __restrict__ sp,     // (N, H*W)
    const void*  __restrict__ spm,    // (N, H*W) mask, 1B or 4B elements
    const unsigned int* __restrict__ bmt,   // (N*NSP) bitmasks
    const unsigned int* __restrict__ flag,
    float* __restrict__ pl, unsigned int* __restrict__ pc,
    unsigned int* __restrict__ st, unsigned int* __restrict__ gt,
    float* __restrict__ out) {

    __shared__ float sL[4];
    __shared__ unsigned int sC[4];

    int b    = blockIdx.x;
    int t    = threadIdx.x;
    int wave = t >> 6;
    unsigned int flagv = *flag;        // hoisted; wave-uniform

    int n  = b >> 8;                   // 256 tiles per image
    int tp = (b & 255) * TILE;         // tile base pixel within image
    size_t gp = (size_t)n * HW_ + tp + 4 * t;   // this thread's 4 pixels

    const float* xb  = x  + (size_t)n * NC * HW_ + tp;
    const int*   spb = sp + (size_t)n * HW_ + tp;
    unsigned int vo  = (unsigned int)(t * 16);  // byte offset

    vf4 d0,d1,d2,d3,d4,d5,d6,d7,d8,d9,d10,d11,d12,d13,d14,d15,d16,d17,d18;
    vi4 s4;

    // 20 dwordx4 back-to-back; vmcnt(19) frees s4 (first issued) so the
    // bitmask gathers + spmask load issue under the remaining stream.
    asm volatile(
        "global_load_dwordx4 %[s4],  %[vo], %[spb]\n\t"
        "global_load_dwordx4 %[d0],  %[vo], %[xb]\n\t"
        "v_add_u32 %[vo], 0x100000, %[vo]\n\t"
        "global_load_dwordx4 %[d1],  %[vo], %[xb]\n\t"
        "v_add_u32 %[vo], 0x100000, %[vo]\n\t"
        "global_load_dwordx4 %[d2],  %[vo], %[xb]\n\t"
        "v_add_u32 %[vo], 0x100000, %[vo]\n\t"
        "global_load_dwordx4 %[d3],  %[vo], %[xb]\n\t"
        "v_add_u32 %[vo], 0x100000, %[vo]\n\t"
        "global_load_dwordx4 %[d4],  %[vo], %[xb]\n\t"
        "v_add_u32 %[vo], 0x100000, %[vo]\n\t"
        "global_load_dwordx4 %[d5],  %[vo], %[xb]\n\t"
        "v_add_u32 %[vo], 0x100000, %[vo]\n\t"
        "global_load_dwordx4 %[d6],  %[vo], %[xb]\n\t"
        "v_add_u32 %[vo], 0x100000, %[vo]\n\t"
        "global_load_dwordx4 %[d7],  %[vo], %[xb]\n\t"
        "v_add_u32 %[vo], 0x100000, %[vo]\n\t"
        "global_load_dwordx4 %[d8],  %[vo], %[xb]\n\t"
        "v_add_u32 %[vo], 0x100000, %[vo]\n\t"
        "global_load_dwordx4 %[d9],  %[vo], %[xb]\n\t"
        "v_add_u32 %[vo], 0x100000, %[vo]\n\t"
        "global_load_dwordx4 %[d10], %[vo], %[xb]\n\t"
        "v_add_u32 %[vo], 0x100000, %[vo]\n\t"
        "global_load_dwordx4 %[d11], %[vo], %[xb]\n\t"
        "v_add_u32 %[vo], 0x100000, %[vo]\n\t"
        "global_load_dwordx4 %[d12], %[vo], %[xb]\n\t"
        "v_add_u32 %[vo], 0x100000, %[vo]\n\t"
        "global_load_dwordx4 %[d13], %[vo], %[xb]\n\t"
        "v_add_u32 %[vo], 0x100000, %[vo]\n\t"
        "global_load_dwordx4 %[d14], %[vo], %[xb]\n\t"
        "v_add_u32 %[vo], 0x100000, %[vo]\n\t"
        "global_load_dwordx4 %[d15], %[vo], %[xb]\n\t"
        "v_add_u32 %[vo], 0x100000, %[vo]\n\t"
        "global_load_dwordx4 %[d16], %[vo], %[xb]\n\t"
        "v_add_u32 %[vo], 0x100000, %[vo]\n\t"
        "global_load_dwordx4 %[d17], %[vo], %[xb]\n\t"
        "v_add_u32 %[vo], 0x100000, %[vo]\n\t"
        "global_load_dwordx4 %[d18], %[vo], %[xb]\n\t"
        "s_waitcnt vmcnt(19)"
        : [d0]"=v"(d0), [d1]"=v"(d1), [d2]"=v"(d2), [d3]"=v"(d3),
          [d4]"=v"(d4), [d5]"=v"(d5), [d6]"=v"(d6), [d7]"=v"(d7),
          [d8]"=v"(d8), [d9]"=v"(d9), [d10]"=v"(d10), [d11]"=v"(d11),
          [d12]"=v"(d12), [d13]"=v"(d13), [d14]"=v"(d14), [d15]"=v"(d15),
          [d16]"=v"(d16), [d17]"=v"(d17), [d18]"=v"(d18),
          [s4]"=v"(s4), [vo]"+v"(vo)
        : [xb]"s"(xb), [spb]"s"(spb));

    // Bitmask gathers (s4 ready; L2-resident) + spmask: issue now, complete
    // under the class stream. Compiler waits guard first use; any extra
    // outstanding loads only make the counted chunk waits MORE conservative.
    const unsigned int* bt = bmt + n * NSP;
    unsigned int bmv0 = bt[s4.x], bmv1 = bt[s4.y],
                 bmv2 = bt[s4.z], bmv3 = bt[s4.w];

    int mk[4];
    if (flagv) {
        vi4 m = *(const vi4*)((const int*)spm + gp);
        mk[0] = m.x; mk[1] = m.y; mk[2] = m.z; mk[3] = m.w;
    } else {
        unsigned int mw = *(const unsigned int*)
                          ((const unsigned char*)spm + gp);
        mk[0] = mw & 0xFF;         mk[1] = (mw >> 8) & 0xFF;
        mk[2] = (mw >> 16) & 0xFF; mk[3] = (mw >> 24) & 0xFF;
    }

    // exp + denominator in ASCENDING class order, chunked on counted vmcnt;
    // in-place exp (no dv copy -> no spill). Register ties pin ordering.
    float se[4] = {0, 0, 0, 0};
#define EXPC(R) { R.x = __expf(R.x); R.y = __expf(R.y);                        \
                  R.z = __expf(R.z); R.w = __expf(R.w);                        \
                  se[0] += R.x; se[1] += R.y; se[2] += R.z; se[3] += R.w; }
    asm volatile("s_waitcnt vmcnt(15)"
                 : "+v"(d0), "+v"(d1), "+v"(d2), "+v"(d3));
    EXPC(d0) EXPC(d1) EXPC(d2) EXPC(d3)
    asm volatile("s_waitcnt vmcnt(11)"
                 : "+v"(d4), "+v"(d5), "+v"(d6), "+v"(d7));
    EXPC(d4) EXPC(d5) EXPC(d6) EXPC(d7)
    asm volatile("s_waitcnt vmcnt(7)"
                 : "+v"(d8), "+v"(d9), "+v"(d10), "+v"(d11));
    EXPC(d8) EXPC(d9) EXPC(d10) EXPC(d11)
    asm volatile("s_waitcnt vmcnt(3)"
                 : "+v"(d12), "+v"(d13), "+v"(d14), "+v"(d15));
    EXPC(d12) EXPC(d13) EXPC(d14) EXPC(d15)
    asm volatile("s_waitcnt vmcnt(0)"
                 : "+v"(d16), "+v"(d17), "+v"(d18));
    EXPC(d16) EXPC(d17) EXPC(d18)
#undef EXPC

    // Numerator pass, ascending class order (bitwise == R1/R3); dv aliases
    // the d-regs (compile-time indices -> no scratch).
    vf4 dv[NC] = {d0,d1,d2,d3,d4,d5,d6,d7,d8,d9,
                  d10,d11,d12,d13,d14,d15,d16,d17,d18};
    float ts[4] = {0, 0, 0, 0};
#pragma unroll
    for (int c = 0; c < NC; ++c) {
        ts[0] += ((bmv0 >> c) & 1) ? dv[c].x : 0.0f;
        ts[1] += ((bmv1 >> c) & 1) ? dv[c].y : 0.0f;
        ts[2] += ((bmv2 >> c) & 1) ? dv[c].z : 0.0f;
        ts[3] += ((bmv3 >> c) & 1) ? dv[c].w : 0.0f;
    }

    float lsum = 0.0f;
    unsigned int lcnt = 0;
    unsigned int bmv[4] = {bmv0, bmv1, bmv2, bmv3};
#pragma unroll
    for (int j = 0; j < 4; ++j) {
        if ((mk[j] != 0) && (bmv[j] != 0u)) {
            lsum -= __logf(ts[j] / se[j] + 1e-8f);
            ++lcnt;
        }
    }

    // ---- wave-64 shuffle reduction -> LDS block reduction ----
    for (int o = 32; o > 0; o >>= 1) {
        lsum += __shfl_down(lsum, o);
        lcnt += __shfl_down(lcnt, o);
    }
    if ((t & 63) == 0) { sL[wave] = lsum; sC[wave] = lcnt; }
    __syncthreads();

    if (t == 0) {
        float        L = sL[0] + sL[1] + sL[2] + sL[3];
        unsigned int C = sC[0] + sC[1] + sC[2] + sC[3];
        __hip_atomic_store(&pl[b], L, __ATOMIC_RELAXED, __HIP_MEMORY_SCOPE_AGENT);
        __hip_atomic_store(&pc[b], C, __ATOMIC_RELAXED, __HIP_MEMORY_SCOPE_AGENT);
        // Hierarchical tickets: 16 groups of 128 (64-B-padded lines), then
        // one super ticket.
        unsigned int g = (unsigned int)b / GSIZE;
        unsigned int isLast = 0u;
        unsigned int tk = __hip_atomic_fetch_add(&gt[g * 16], 1u,
                              __ATOMIC_ACQ_REL, __HIP_MEMORY_SCOPE_AGENT);
        if (tk == (unsigned int)(GSIZE - 1)) {
            unsigned int s = __hip_atomic_fetch_add(st, 1u,
                                 __ATOMIC_ACQ_REL, __HIP_MEMORY_SCOPE_AGENT);
            isLast = (s == NGRP - 1) ? 1u : 0u;
        }
        sC[0] = isLast;                // reuse LDS as broadcast
    }
    __syncthreads();

    // Last block: reduce the 2048 partials and write the scalar.
    if (sC[0]) {
        float        L = 0.0f;
        unsigned int C = 0u;
        for (int i = t; i < NBLK; i += 256) {
            L += __hip_atomic_load(&pl[i], __ATOMIC_RELAXED, __HIP_MEMORY_SCOPE_AGENT);
            C += __hip_atomic_load(&pc[i], __ATOMIC_RELAXED, __HIP_MEMORY_SCOPE_AGENT);
        }
        for (int o = 32; o > 0; o >>= 1) {
            L += __shfl_down(L, o);
            C += __shfl_down(C, o);
        }
        __syncthreads();               // LDS reuse barrier
        if ((t & 63) == 0) { sL[wave] = L; sC[wave] = C; }
        __syncthreads();
        if (t == 0) {
            L = sL[0] + sL[1] + sL[2] + sL[3];
            C = sC[0] + sC[1] + sC[2] + sC[3];
            out[0] = L / (float)(1u + C);
        }
    }
}

extern "C" void kernel_launch(void* const* d_in, const int* in_sizes, int n_in,
                              void* d_out, int out_size, void* d_ws, size_t ws_size,
                              hipStream_t stream) {
    const float* x   = (const float*)d_in[0];   // inputs (8,19,512,512) f32
    const float* tgt = (const float*)d_in[1];   // targets (8,2048,20) f32
    const int*   sp  = (const int*)d_in[2];     // superpixels (8,512,512) i32
    const void*  spm = d_in[3];                 // spmasks (8,512,512), width detected

    unsigned int* flag = (unsigned int*)d_ws;
    unsigned int* st   = (unsigned int*)((char*)d_ws + 4);
    unsigned int* gt   = (unsigned int*)((char*)d_ws + 64);
    float*        pl   = (float*)((char*)d_ws + 1088);
    unsigned int* pc   = (unsigned int*)((char*)d_ws + 9280);
    unsigned int* bmt  = (unsigned int*)((char*)d_ws + 17472);

    prep<<<NROWS / 256, 256, 0, stream>>>(tgt, (const unsigned int*)spm,
                                          flag, st, gt, bmt);

    mcce_main<<<NBLK, 256, 0, stream>>>(x, sp, spm, bmt, flag,
                                        pl, pc, st, gt, (float*)d_out);
}

// Round 6
// 247.145 us; speedup vs baseline: 1.3502x; 1.3502x over previous
//
#include <hip/hip_runtime.h>

#define HW_   (512 * 512)   // pixels per image
#define NIMG  8
#define NC    19            // classes
#define NSP   2048          // superpixels per image
#define TC    20            // target row stride (C+1, last col sliced off)
#define NROWS (NIMG * NSP)  // 16384 target rows
#define TILE  1024          // pixels per tile (4 per thread)
#define NTILE (NIMG * HW_ / TILE)   // 2048 tiles
#define NBLK  256           // persistent blocks: ONE per CU
#define NITER (NTILE / NBLK)        // 8 tiles per block; iter == one image
#define NGRP  16            // completion-ticket groups (16 blocks each)
#define GSIZE (NBLK / NGRP)

typedef float vf4 __attribute__((ext_vector_type(4)));
typedef int   vi4 __attribute__((ext_vector_type(4)));

// d_ws layout:
//   [0]    flag (uint)       spmask width: 1 -> 4-byte, 0 -> 1-byte
//   [4]    st   (uint)       super ticket
//   [64]   gt[NGRP] uints, stride 16 (64 B apart -> no same-line RMWs)
//   [1088] pl[NBLK] float    per-block loss partials (contention-free)
//   [3136] pc[NBLK] uint     per-block count partials
//   [5184] bmt[NROWS] uint   per-(image,superpixel) multi-hot bitmask

// ---------------------------------------------------------------------------
// Kernel 1: zero tickets, detect spmask width, build target bitmasks.
// ---------------------------------------------------------------------------
__global__ __launch_bounds__(256) void prep(
    const float* __restrict__ tgt,
    const unsigned int* __restrict__ spm,
    unsigned int* __restrict__ flag, unsigned int* __restrict__ st,
    unsigned int* __restrict__ gt, unsigned int* __restrict__ bm) {

    int gid = blockIdx.x * 256 + threadIdx.x;   // 64 blocks -> 16384 threads
    if (gid == 0) *st = 0u;
    if (gid < NGRP) gt[gid * 16] = 0u;

    if (blockIdx.x == 1 && threadIdx.x < 64) {  // one wave: width detection
        unsigned int nonlow = 0, upper = 0;
        for (int i = threadIdx.x; i < 1024; i += 64) {
            unsigned int v = spm[i];
            nonlow |= (v & 0xFEFEFEFEu);
            upper  |= (v & 0xFFFFFF00u);
        }
        unsigned long long b1 = __ballot(nonlow != 0);
        unsigned long long b2 = __ballot(upper != 0);
        if (threadIdx.x == 0)
            *flag = ((b1 == 0ull) && (b2 != 0ull)) ? 0u : 1u;
    }

    const float* row = tgt + (size_t)gid * TC;  // one thread per target row
    unsigned int m = 0;
#pragma unroll
    for (int c = 0; c < NC; ++c)
        m |= (row[c] != 0.0f ? 1u : 0u) << c;
    bm[gid] = m;
}

// ---------------------------------------------------------------------------
// Kernel 2: persistent-block, IMAGE-SERIAL fused exp-sum + gather + NLL.
// ONE block per CU (256 blocks); block b processes tile b of image `it`,
// it = 0..7 -> each iteration is exactly one image chip-wide. Rationale:
// across 6 structurally diverse variants the ONLY monotone lever is
// resident blocks/CU: 2/CU ~1.9 TB/s delivered, 4/CU 1.45, one-shot churn
// 1.05 -- some shared per-CU/XCD memory-queue resource degrades with
// concurrent stream count. This is the 1/CU extreme: 20 live streams per
// CU, deepest per-wave bursts, zero block churn.
// __launch_bounds__(256,1) lifts the VGPR cap (~512/wave at 1 wave/SIMD):
// the dv[NC] alias copy stays in registers -> no scratch spill (R1's 96 MB
// WRITE_SIZE came from the 64-VGPR cap), freeing the write path.
// The 20-load burst (sp + 19 class rows, dwordx4) stays a single asm block:
// indivisible, outputs live, one trailing s_waitcnt vmcnt(0) (the measured-
// fastest consumption across R1..R5 -- counted chunks were neutral/worse).
// ---------------------------------------------------------------------------
__global__ __launch_bounds__(256, 1) void mcce_main(
    const float* __restrict__ x,      // (N, C, H*W)
    const int*   __restrict__ sp,     // (N, H*W)
    const void*  __restrict__ spm,    // (N, H*W) mask, 1B or 4B elements
    const unsigned int* __restrict__ bmt,   // (N*NSP) bitmasks
    const unsigned int* __restrict__ flag,
    float* __restrict__ pl, unsigned int* __restrict__ pc,
    unsigned int* __restrict__ st, unsigned int* __restrict__ gt,
    float* __restrict__ out) {

    __shared__ float sL[4];
    __shared__ unsigned int sC[4];

    int b    = blockIdx.x;
    int t    = threadIdx.x;
    int wave = t >> 6;
    unsigned int flagv = *flag;        // hoisted; wave-uniform

    float lsum = 0.0f;
    unsigned int lcnt = 0;

#pragma unroll 1
    for (int it = 0; it < NITER; ++it) {
        int T  = it * NBLK + b;        // NBLK=256 -> n = it, tile b of image it
        int n  = T >> 8;               // 256 tiles per image
        int tp = (T & 255) * TILE;     // tile base pixel within image
        size_t gp = (size_t)n * HW_ + tp + 4 * t;   // this thread's 4 pixels

        const float* xb  = x  + (size_t)n * NC * HW_ + tp;
        const int*   spb = sp + (size_t)n * HW_ + tp;
        unsigned int vo  = (unsigned int)(t * 16);  // byte offset

        vf4 d0,d1,d2,d3,d4,d5,d6,d7,d8,d9,d10,d11,d12,d13,d14,d15,d16,d17,d18;
        vi4 s4;

        // 20 dwordx4 loads back-to-back, one wait. Class stride = 1 MB.
        asm volatile(
            "global_load_dwordx4 %[s4],  %[vo], %[spb]\n\t"
            "global_load_dwordx4 %[d0],  %[vo], %[xb]\n\t"
            "v_add_u32 %[vo], 0x100000, %[vo]\n\t"
            "global_load_dwordx4 %[d1],  %[vo], %[xb]\n\t"
            "v_add_u32 %[vo], 0x100000, %[vo]\n\t"
            "global_load_dwordx4 %[d2],  %[vo], %[xb]\n\t"
            "v_add_u32 %[vo], 0x100000, %[vo]\n\t"
            "global_load_dwordx4 %[d3],  %[vo], %[xb]\n\t"
            "v_add_u32 %[vo], 0x100000, %[vo]\n\t"
            "global_load_dwordx4 %[d4],  %[vo], %[xb]\n\t"
            "v_add_u32 %[vo], 0x100000, %[vo]\n\t"
            "global_load_dwordx4 %[d5],  %[vo], %[xb]\n\t"
            "v_add_u32 %[vo], 0x100000, %[vo]\n\t"
            "global_load_dwordx4 %[d6],  %[vo], %[xb]\n\t"
            "v_add_u32 %[vo], 0x100000, %[vo]\n\t"
            "global_load_dwordx4 %[d7],  %[vo], %[xb]\n\t"
            "v_add_u32 %[vo], 0x100000, %[vo]\n\t"
            "global_load_dwordx4 %[d8],  %[vo], %[xb]\n\t"
            "v_add_u32 %[vo], 0x100000, %[vo]\n\t"
            "global_load_dwordx4 %[d9],  %[vo], %[xb]\n\t"
            "v_add_u32 %[vo], 0x100000, %[vo]\n\t"
            "global_load_dwordx4 %[d10], %[vo], %[xb]\n\t"
            "v_add_u32 %[vo], 0x100000, %[vo]\n\t"
            "global_load_dwordx4 %[d11], %[vo], %[xb]\n\t"
            "v_add_u32 %[vo], 0x100000, %[vo]\n\t"
            "global_load_dwordx4 %[d12], %[vo], %[xb]\n\t"
            "v_add_u32 %[vo], 0x100000, %[vo]\n\t"
            "global_load_dwordx4 %[d13], %[vo], %[xb]\n\t"
            "v_add_u32 %[vo], 0x100000, %[vo]\n\t"
            "global_load_dwordx4 %[d14], %[vo], %[xb]\n\t"
            "v_add_u32 %[vo], 0x100000, %[vo]\n\t"
            "global_load_dwordx4 %[d15], %[vo], %[xb]\n\t"
            "v_add_u32 %[vo], 0x100000, %[vo]\n\t"
            "global_load_dwordx4 %[d16], %[vo], %[xb]\n\t"
            "v_add_u32 %[vo], 0x100000, %[vo]\n\t"
            "global_load_dwordx4 %[d17], %[vo], %[xb]\n\t"
            "v_add_u32 %[vo], 0x100000, %[vo]\n\t"
            "global_load_dwordx4 %[d18], %[vo], %[xb]\n\t"
            "s_waitcnt vmcnt(0)"
            : [d0]"=v"(d0), [d1]"=v"(d1), [d2]"=v"(d2), [d3]"=v"(d3),
              [d4]"=v"(d4), [d5]"=v"(d5), [d6]"=v"(d6), [d7]"=v"(d7),
              [d8]"=v"(d8), [d9]"=v"(d9), [d10]"=v"(d10), [d11]"=v"(d11),
              [d12]"=v"(d12), [d13]"=v"(d13), [d14]"=v"(d14), [d15]"=v"(d15),
              [d16]"=v"(d16), [d17]"=v"(d17), [d18]"=v"(d18),
              [s4]"=v"(s4), [vo]"+v"(vo)
            : [xb]"s"(xb), [spb]"s"(spb));

        // Mask (wave-uniform width branch) + bitmask gathers (L2-resident).
        int mk[4];
        if (flagv) {
            vi4 m = *(const vi4*)((const int*)spm + gp);
            mk[0] = m.x; mk[1] = m.y; mk[2] = m.z; mk[3] = m.w;
        } else {
            unsigned int mw = *(const unsigned int*)
                              ((const unsigned char*)spm + gp);
            mk[0] = mw & 0xFF; mk[1] = (mw >> 8) & 0xFF;
            mk[2] = (mw >> 16) & 0xFF; mk[3] = (mw >> 24) & 0xFF;
        }
        const unsigned int* bt = bmt + n * NSP;
        unsigned int bmv[4] = {bt[s4.x], bt[s4.y], bt[s4.z], bt[s4.w]};

        // Streaming exp-sums (no max-subtraction: inputs ~N(0,1), fp32-safe).
        vf4 dv[NC] = {d0,d1,d2,d3,d4,d5,d6,d7,d8,d9,
                      d10,d11,d12,d13,d14,d15,d16,d17,d18};
        float se[4] = {0,0,0,0}, ts[4] = {0,0,0,0};
#pragma unroll
        for (int c = 0; c < NC; ++c) {
            float e0 = __expf(dv[c].x), e1 = __expf(dv[c].y);
            float e2 = __expf(dv[c].z), e3 = __expf(dv[c].w);
            se[0] += e0; se[1] += e1; se[2] += e2; se[3] += e3;
            ts[0] += ((bmv[0] >> c) & 1) ? e0 : 0.0f;
            ts[1] += ((bmv[1] >> c) & 1) ? e1 : 0.0f;
            ts[2] += ((bmv[2] >> c) & 1) ? e2 : 0.0f;
            ts[3] += ((bmv[3] >> c) & 1) ? e3 : 0.0f;
        }
#pragma unroll
        for (int j = 0; j < 4; ++j) {
            if ((mk[j] != 0) && (bmv[j] != 0u)) {
                lsum -= __logf(ts[j] / se[j] + 1e-8f);
                ++lcnt;
            }
        }
    }

    // Wave-64 shuffle reduction -> LDS block reduction.
    for (int o = 32; o > 0; o >>= 1) {
        lsum += __shfl_down(lsum, o);
        lcnt += __shfl_down(lcnt, o);
    }
    if ((t & 63) == 0) { sL[wave] = lsum; sC[wave] = lcnt; }
    __syncthreads();

    if (t == 0) {
        float        L = sL[0] + sL[1] + sL[2] + sL[3];
        unsigned int C = sC[0] + sC[1] + sC[2] + sC[3];
        // Private slot per block -> zero contention; agent scope for
        // cross-XCD visibility to the finalizing block.
        __hip_atomic_store(&pl[b], L, __ATOMIC_RELAXED,
                           __HIP_MEMORY_SCOPE_AGENT);
        __hip_atomic_store(&pc[b], C, __ATOMIC_RELAXED,
                           __HIP_MEMORY_SCOPE_AGENT);
        // Hierarchical tickets: 16 groups of 16 (64-B-padded lines), then
        // one super ticket -> max ~16 same-line RMWs anywhere.
        unsigned int g = (unsigned int)b / GSIZE;
        unsigned int isLast = 0u;
        unsigned int tk = __hip_atomic_fetch_add(&gt[g * 16], 1u,
                              __ATOMIC_ACQ_REL, __HIP_MEMORY_SCOPE_AGENT);
        if (tk == (unsigned int)(GSIZE - 1)) {
            unsigned int s = __hip_atomic_fetch_add(st, 1u,
                                 __ATOMIC_ACQ_REL, __HIP_MEMORY_SCOPE_AGENT);
            isLast = (s == NGRP - 1) ? 1u : 0u;
        }
        sC[0] = isLast;                // reuse LDS as broadcast
    }
    __syncthreads();

    // Last block: reduce the 256 partials and write the scalar.
    if (sC[0]) {
        float        L = 0.0f;
        unsigned int C = 0u;
        for (int i = t; i < NBLK; i += 256) {
            L += __hip_atomic_load(&pl[i], __ATOMIC_RELAXED,
                                   __HIP_MEMORY_SCOPE_AGENT);
            C += __hip_atomic_load(&pc[i], __ATOMIC_RELAXED,
                                   __HIP_MEMORY_SCOPE_AGENT);
        }
        for (int o = 32; o > 0; o >>= 1) {
            L += __shfl_down(L, o);
            C += __shfl_down(C, o);
        }
        __syncthreads();               // LDS reuse barrier
        if ((t & 63) == 0) { sL[wave] = L; sC[wave] = C; }
        __syncthreads();
        if (t == 0) {
            L = sL[0] + sL[1] + sL[2] + sL[3];
            C = sC[0] + sC[1] + sC[2] + sC[3];
            out[0] = L / (float)(1u + C);
        }
    }
}

extern "C" void kernel_launch(void* const* d_in, const int* in_sizes, int n_in,
                              void* d_out, int out_size, void* d_ws, size_t ws_size,
                              hipStream_t stream) {
    const float* x   = (const float*)d_in[0];   // inputs (8,19,512,512) f32
    const float* tgt = (const float*)d_in[1];   // targets (8,2048,20) f32
    const int*   sp  = (const int*)d_in[2];     // superpixels (8,512,512) i32
    const void*  spm = d_in[3];                 // spmasks (8,512,512), width detected

    unsigned int* flag = (unsigned int*)d_ws;
    unsigned int* st   = (unsigned int*)((char*)d_ws + 4);
    unsigned int* gt   = (unsigned int*)((char*)d_ws + 64);
    float*        pl   = (float*)((char*)d_ws + 1088);
    unsigned int* pc   = (unsigned int*)((char*)d_ws + 3136);
    unsigned int* bmt  = (unsigned int*)((char*)d_ws + 5184);

    prep<<<NROWS / 256, 256, 0, stream>>>(tgt, (const unsigned int*)spm,
                                          flag, st, gt, bmt);

    mcce_main<<<NBLK, 256, 0, stream>>>(x, sp, spm, bmt, flag,
                                        pl, pc, st, gt, (float*)d_out);
}